// Round 4
// baseline (5442.670 us; speedup 1.0000x reference)
//
#include <hip/hip_runtime.h>

// LSTM b=32, t=1024, din=512, hid=1024. Persistent cooperative kernel:
// 128 blocks x 256 threads, each block owns 8 hidden units (32 gate cols),
// weights (K=1536 x 32 cols, bf16) resident in LDS.
//
// R4 protocol: NO flags, NO publish ack. hbuf is a depth-2 ring of bf16
// whose LSB carries a step-parity tag ((t>>1)&1 — alternates on every reuse
// of a slot). Producers fire-and-forget tagged sc1 stores right after the
// pointwise; consumers' data loads ARE the poll: validate LSBs in registers,
// exec-masked reload of only the stale chunks. Cuts the R3 chain of ~4-5
// device-scope round trips per step to ~1.5.

#define T_STEPS 1024
#define BATCH   32
#define DIN     512
#define HID     1024
#define KTOT    1536
#define NBLK    128
#define WCOLS   32          // gate cols per block
#define WSTR    1544        // shorts per col in LDS (16B-aligned rows)
#define REDSTR  35          // padded fp32 reduction row stride (3*pb+pu bank spread)
#define REDW    (32*REDSTR) // floats per wave in reduction buffer

#define LDS_W_BYTES   (WCOLS*WSTR*2)        // 98816
#define LDS_RED_BYTES (4*REDW*4)            // 17920
#define LDS_TOTAL     (LDS_W_BYTES + LDS_RED_BYTES)  // 116736

typedef __attribute__((ext_vector_type(8))) short  short8;
typedef __attribute__((ext_vector_type(4))) float  floatx4;
typedef __attribute__((ext_vector_type(4))) unsigned int uint4v;
typedef __attribute__((ext_vector_type(4))) unsigned short ushort4_;

__device__ __forceinline__ unsigned short f2bf(float f) {
    unsigned u = __builtin_bit_cast(unsigned, f);
    u += 0x7FFFu + ((u >> 16) & 1u);
    return (unsigned short)(u >> 16);
}
__device__ __forceinline__ float sigf(float x) { return 1.f / (1.f + __expf(-x)); }

// ---- device-scope (L3 coherence point) access helpers: sc1 ----
__device__ __forceinline__ floatx4 coh_load16(const void* p) {
    floatx4 v;
    asm volatile("global_load_dwordx4 %0, %1, off sc1" : "=v"(v) : "v"(p) : "memory");
    return v;
}
__device__ __forceinline__ void coh_store2(void* p, unsigned short v) {
    asm volatile("global_store_short %0, %1, off sc1" :: "v"(p), "v"((unsigned)v) : "memory");
}
__device__ __forceinline__ void wait_vm0() {
    asm volatile("s_waitcnt vmcnt(0)" ::: "memory");
}

// ---- prep: kernel [1536][4096] fp32 -> wt [4096 cols][1536 k] bf16 (transposed) ----
__global__ __launch_bounds__(256) void prep_wt(const float* __restrict__ kern,
                                               unsigned short* __restrict__ wt) {
    __shared__ unsigned short tile[64][72];
    const int c0 = (blockIdx.x & 63) * 64;
    const int k0 = (blockIdx.x >> 6) * 64;
    const int cl = threadIdx.x & 63;
    const int kg = threadIdx.x >> 6;
    #pragma unroll
    for (int i = 0; i < 16; ++i) {
        int kl = kg * 16 + i;
        tile[cl][kl] = f2bf(kern[(k0 + kl) * 4096 + c0 + cl]);
    }
    __syncthreads();
    #pragma unroll
    for (int i = 0; i < 16; ++i) {
        int cc = kg * 16 + i;
        wt[(size_t)(c0 + cc) * KTOT + k0 + cl] = tile[cc][cl];
    }
}

// ---- prep: x [32][1024][512] fp32 -> xT [1024][32][512] bf16 ----
__global__ __launch_bounds__(256) void prep_x(const float* __restrict__ x,
                                              unsigned short* __restrict__ xT) {
    const int row = blockIdx.x * 2 + (threadIdx.x >> 7);
    const int l   = threadIdx.x & 127;
    const int b = row >> 10, t = row & 1023;
    float4 v = ((const float4*)(x + (size_t)row * DIN))[l];
    ushort4_ o;
    o.x = f2bf(v.x); o.y = f2bf(v.y); o.z = f2bf(v.z); o.w = f2bf(v.w);
    *(ushort4_*)(xT + ((size_t)t * BATCH + b) * DIN + l * 4) = o;
}

// ---- prep: slot0 = tile(h_init) tagged LSB=0 (t=0 tag); slot1 = LSB=1 (reject) ----
__global__ __launch_bounds__(256) void init_h(const float* __restrict__ h_init,
                                              unsigned short* __restrict__ hbuf) {
    const int b = blockIdx.x;
    for (int u = threadIdx.x; u < HID; u += 256) {
        hbuf[b * HID + u] = (unsigned short)(f2bf(h_init[u]) & 0xFFFEu);  // tag 0
        hbuf[BATCH * HID + b * HID + u] = 0x0001;                         // tag 1
    }
}

// ---- persistent LSTM ----
__global__ __launch_bounds__(256, 1) void lstm_persist(
    const unsigned short* __restrict__ wt,   // [4096][1536] bf16
    const unsigned short* __restrict__ xT,   // [1024][32][512] bf16
    unsigned short* __restrict__ hbuf,       // [2][32][1024] bf16, LSB = parity tag
    const float* __restrict__ bias,          // [4096]
    float* __restrict__ out)                 // [32][1024][1024] fp32
{
    extern __shared__ char smem[];
    unsigned short* ldsW = (unsigned short*)smem;
    float* red = (float*)(smem + LDS_W_BYTES);

    const int bk   = blockIdx.x;
    const int tid  = threadIdx.x;
    const int wave = tid >> 6;
    const int lane = tid & 63;
    const int lrow = lane & 15;   // m (batch) / n (col) index within 16-tile
    const int kq   = lane >> 4;   // k quad, each holds 8 contiguous k

    // Stage this block's 32 weight columns into LDS: cols {g*1024 + bk*8 + u}
    for (int cl = wave; cl < WCOLS; cl += 4) {
        const int gcol = (cl >> 3) * HID + bk * 8 + (cl & 7);
        const unsigned short* src = wt + (size_t)gcol * KTOT;
        unsigned short* dst = ldsW + cl * WSTR;
        for (int k = lane * 8; k < KTOT; k += 512)
            *(short8*)(dst + k) = *(const short8*)(src + k);
    }

    // Pointwise thread mapping: thread = (batch pb, unit-offset pu)
    const int pb = tid >> 3;
    const int pu = tid & 7;
    float bias_r[4];
    #pragma unroll
    for (int g = 0; g < 4; ++g) bias_r[g] = bias[g * HID + bk * 8 + pu];
    float c_state = 0.f;
    __syncthreads();

    for (int t = 0; t < T_STEPS; ++t) {
        floatx4 zero = {0.f, 0.f, 0.f, 0.f};
        floatx4 acc[2][2];
        acc[0][0] = zero; acc[0][1] = zero; acc[1][0] = zero; acc[1][1] = zero;

        // ---- x-part of K (k in [0,512)) — independent of h ----
        const unsigned short* xb = xT + (size_t)t * (BATCH * DIN);
        #pragma unroll
        for (int i = 0; i < 4; ++i) {
            const int kl = wave * 128 + i * 32 + kq * 8;
            short8 a0 = *(const short8*)(xb + lrow * DIN + kl);
            short8 a1 = *(const short8*)(xb + (lrow + 16) * DIN + kl);
            short8 b0 = *(const short8*)(ldsW + lrow * WSTR + kl);
            short8 b1 = *(const short8*)(ldsW + (lrow + 16) * WSTR + kl);
            acc[0][0] = __builtin_amdgcn_mfma_f32_16x16x32_bf16(a0, b0, acc[0][0], 0, 0, 0);
            acc[0][1] = __builtin_amdgcn_mfma_f32_16x16x32_bf16(a0, b1, acc[0][1], 0, 0, 0);
            acc[1][0] = __builtin_amdgcn_mfma_f32_16x16x32_bf16(a1, b0, acc[1][0], 0, 0, 0);
            acc[1][1] = __builtin_amdgcn_mfma_f32_16x16x32_bf16(a1, b1, acc[1][1], 0, 0, 0);
        }

        // ---- h-part: load-validate-retry (the load IS the poll) ----
        const unsigned short* hb = hbuf + (size_t)(t & 1) * (BATCH * HID);
        const unsigned tagm = ((t >> 1) & 1) ? 0x00010001u : 0u;
        const int tag1 = (t >> 1) & 1;
        floatx4 ha[8][2];
        #pragma unroll
        for (int i = 0; i < 8; ++i) {
            const int kh = wave * 256 + i * 32 + kq * 8;
            ha[i][0] = coh_load16(hb + lrow * HID + kh);
            ha[i][1] = coh_load16(hb + (lrow + 16) * HID + kh);
        }
        wait_vm0();
        for (;;) {
            int bad = 0;
            #pragma unroll
            for (int i = 0; i < 8; ++i) {
                const int kh = wave * 256 + i * 32 + kq * 8;
                #pragma unroll
                for (int j = 0; j < 2; ++j) {
                    uint4v d = __builtin_bit_cast(uint4v, ha[i][j]);
                    unsigned c = tag1 ? (d.x & d.y & d.z & d.w)
                                      : (d.x | d.y | d.z | d.w);
                    if ((c & 0x00010001u) != tagm) {
                        ha[i][j] = coh_load16(hb + (lrow + j * 16) * HID + kh);
                        bad = 1;
                    }
                }
            }
            if (!__any(bad)) break;
            wait_vm0();
        }
        #pragma unroll
        for (int i = 0; i < 8; ++i) {
            const int kw = 512 + wave * 256 + i * 32 + kq * 8;
            short8 a0 = __builtin_bit_cast(short8, ha[i][0]);
            short8 a1 = __builtin_bit_cast(short8, ha[i][1]);
            short8 b0 = *(const short8*)(ldsW + lrow * WSTR + kw);
            short8 b1 = *(const short8*)(ldsW + (lrow + 16) * WSTR + kw);
            acc[0][0] = __builtin_amdgcn_mfma_f32_16x16x32_bf16(a0, b0, acc[0][0], 0, 0, 0);
            acc[0][1] = __builtin_amdgcn_mfma_f32_16x16x32_bf16(a0, b1, acc[0][1], 0, 0, 0);
            acc[1][0] = __builtin_amdgcn_mfma_f32_16x16x32_bf16(a1, b0, acc[1][0], 0, 0, 0);
            acc[1][1] = __builtin_amdgcn_mfma_f32_16x16x32_bf16(a1, b1, acc[1][1], 0, 0, 0);
        }

        // ---- cross-wave K reduction via LDS ----
        #pragma unroll
        for (int mt = 0; mt < 2; ++mt)
            #pragma unroll
            for (int nt = 0; nt < 2; ++nt)
                #pragma unroll
                for (int r = 0; r < 4; ++r) {
                    const int row = mt * 16 + kq * 4 + r;   // C/D: row=(lane>>4)*4+reg
                    const int col = nt * 16 + lrow;         //      col=lane&15
                    red[wave * REDW + row * REDSTR + col] = acc[mt][nt][r];
                }
        __syncthreads();   // barrier A: all partials visible

        // ---- pointwise: gates -> c,h; publish immediately (fire-and-forget) ----
        float gv[4];
        #pragma unroll
        for (int g = 0; g < 4; ++g) {
            const int col = g * 8 + pu;
            float s = bias_r[g];
            #pragma unroll
            for (int w = 0; w < 4; ++w) s += red[w * REDW + pb * REDSTR + col];
            gv[g] = s;
        }
        const float fg = sigf(gv[0]);
        const float ig = sigf(gv[1]);
        const float og = sigf(gv[2]);
        const float gg = tanhf(gv[3]);
        c_state = fg * c_state + ig * gg;
        const float hn = og * tanhf(c_state);

        const unsigned tagN = (unsigned)(((t + 1) >> 1) & 1);
        unsigned short hv = (unsigned short)((f2bf(hn) & 0xFFFEu) | tagN);
        unsigned short* hp = hbuf + (size_t)((t + 1) & 1) * (BATCH * HID)
                                  + pb * HID + bk * 8 + pu;
        coh_store2(hp, hv);   // publish: no ack, no flag — LSB tag validates

        out[(size_t)pb * (T_STEPS * HID) + (size_t)t * HID + bk * 8 + pu] = hn;

        __syncthreads();   // barrier B: red safe to reuse next step
    }
}

extern "C" void kernel_launch(void* const* d_in, const int* in_sizes, int n_in,
                              void* d_out, int out_size, void* d_ws, size_t ws_size,
                              hipStream_t stream) {
    (void)in_sizes; (void)n_in; (void)out_size;
    const float* x      = (const float*)d_in[0];
    // d_in[1] = input_paddings (all zero, unused per reference)
    const float* kern   = (const float*)d_in[2];
    const float* bias   = (const float*)d_in[3];
    const float* h_init = (const float*)d_in[4];
    float* out = (float*)d_out;

    char* ws = (char*)d_ws;
    unsigned short* wt    = (unsigned short*)(ws);                       // 12,582,912 B
    unsigned short* xT    = (unsigned short*)(ws + 12582912);            // 33,554,432 B
    unsigned short* hbuf  = (unsigned short*)(ws + 12582912 + 33554432); //    131,072 B
    (void)ws_size;

    hipFuncSetAttribute((const void*)lstm_persist,
                        hipFuncAttributeMaxDynamicSharedMemorySize, LDS_TOTAL);

    prep_wt<<<dim3(64 * 24), dim3(256), 0, stream>>>(kern, wt);
    prep_x<<<dim3(BATCH * T_STEPS / 2), dim3(256), 0, stream>>>(x, xT);
    init_h<<<dim3(32), dim3(256), 0, stream>>>(h_init, hbuf);

    void* args[] = { &wt, &xT, &hbuf, &bias, &out };
    hipLaunchCooperativeKernel((const void*)lstm_persist, dim3(NBLK), dim3(256),
                               args, LDS_TOTAL, stream);
}